// Round 19
// baseline (588.413 us; speedup 1.0000x reference)
//
#include <hip/hip_runtime.h>
#include <hip/hip_bf16.h>
#include <cstdint>
#include <cstddef>

// ws layout (float offsets)
#define WS_BMAT 0            // bmatT: 24*640 = 15360
#define WS_BBIG 15360        // 24 (+pad to 64)
#define WS_WBT  15424        // wbT bf16 [32][3072] = 98304 ushort = 49152 floats
#define WS_ND   64576        // 8*8192*23 = 1507328
#define WS_ED   1571904      // 4*28672*23 = 2637824  (end 4209728 floats)

// output offsets (floats)
#define OUT_IND 0
#define OUT_LAB 28672
#define OUT_LRP 57344
#define OUT_CRP 98304
#define OUT_MRP 122880
#define OUT_LRN 237568
#define OUT_CRN 339968
#define OUT_MRN 401408

typedef __attribute__((ext_vector_type(8))) short bf16x8;
typedef __attribute__((ext_vector_type(4))) float f32x4;

__device__ __constant__ int d_pi[28] = {0,0,0,0,0,0,0,1,1,1,1,1,1,2,2,2,2,2,3,3,3,3,4,4,4,5,5,6};
__device__ __constant__ int d_pj[28] = {1,2,3,4,5,6,7,2,3,4,5,6,7,3,4,5,6,7,4,5,6,7,5,6,7,6,7,7};

__device__ __forceinline__ float wh_at(const float* wlr, const float* wcr, const float* wmr,
                                       int j, int h) {
  return (h < 5) ? wlr[j*5 + h] : (h < 8) ? wcr[j*3 + (h-5)] : wmr[j*14 + (h-8)];
}

__device__ __forceinline__ short f2bf(float f) {
  __hip_bfloat16 h = __float2bfloat16(f);
  short s;
  __builtin_memcpy(&s, &h, 2);
  return s;
}
__device__ __forceinline__ unsigned int f2bfu(float f) {
  __hip_bfloat16 h = __float2bfloat16(f);
  unsigned short s;
  __builtin_memcpy(&s, &h, 2);
  return (unsigned int)s;
}

// ---------------- prep1: bmatT[24][640] and b_big ----------------
__global__ __launch_bounds__(256) void prep1(
    const float* __restrict__ w_rel, const float* __restrict__ w_ind2,
    const float* __restrict__ w_lr, const float* __restrict__ w_cr, const float* __restrict__ w_mr,
    const float* __restrict__ b_ind1, const float* __restrict__ b_ind2,
    const float* __restrict__ b_rel,
    const float* __restrict__ b_lr, const float* __restrict__ b_cr, const float* __restrict__ b_mr,
    float* __restrict__ bmat, float* __restrict__ bbig) {
  int bid = blockIdx.x, tid = threadIdx.x;
  if (bid < 128) {
    int m = bid;
    __shared__ float swr[512];
    const float* wr2 = w_rel + (size_t)(3072 + m)*512;
    swr[tid]       = wr2[tid];
    swr[tid + 256] = wr2[tid + 256];
    __syncthreads();
    int h = tid >> 3, q = tid & 7;
    if (h < 22) {
      float a = 0.f;
#pragma unroll 8
      for (int jj = 0; jj < 64; ++jj) {
        int j = jj*8 + q;
        a = fmaf(swr[j], wh_at(w_lr, w_cr, w_mr, j, h), a);
      }
      a += __shfl_xor(a, 1); a += __shfl_xor(a, 2); a += __shfl_xor(a, 4);
      if (q == 0) bmat[(1 + h)*640 + m] = a;
    }
    if (tid == 248) bmat[0*640 + m]  = w_ind2[m];
    if (tid == 249) bmat[23*640 + m] = 0.f;
  } else if (bid == 128) {
    __shared__ float sbrel[512];
    for (int j = tid; j < 512; j += 256) {
      float a = b_rel[j];
#pragma unroll 4
      for (int m = 0; m < 128; ++m)
        a = fmaf(b_ind1[m], w_rel[(size_t)(3072 + m)*512 + j], a);
      sbrel[j] = a;
    }
    __syncthreads();
    int h = tid >> 3, q = tid & 7;
    if (h < 22) {
      float bh = (h < 5) ? b_lr[h] : (h < 8) ? b_cr[h-5] : b_mr[h-8];
      float a = 0.f;
#pragma unroll 8
      for (int jj = 0; jj < 64; ++jj) {
        int j = jj*8 + q;
        a = fmaf(sbrel[j], wh_at(w_lr, w_cr, w_mr, j, h), a);
      }
      a += __shfl_xor(a, 1); a += __shfl_xor(a, 2); a += __shfl_xor(a, 4);
      if (q == 0) bbig[1 + h] = a + bh;
    } else if (tid >= 248) {
      int q2 = tid & 7;
      float a = 0.f;
#pragma unroll
      for (int t = 0; t < 16; ++t)
        a = fmaf(b_ind1[q2*16 + t], w_ind2[q2*16 + t], a);
      a += __shfl_xor(a, 1); a += __shfl_xor(a, 2); a += __shfl_xor(a, 4);
      if (tid == 248) bbig[0]  = a + b_ind2[0];
      if (tid == 250) bbig[23] = 0.f;
    }
  } else {
    int idx = (bid - 129)*256 + tid;
    int j = idx / 24, n = idx % 24;
    float v = (n >= 1 && n <= 22) ? wh_at(w_lr, w_cr, w_mr, j, n - 1) : 0.f;
    bmat[n*640 + 128 + j] = v;
  }
}

// ---------------- prep2m: W_big via MFMA (M=3072 k-rows, N=32, K=640) ----------------
// Reuses kmain's verified fragment mapping: A lane=row(ln), k-slots lg*8; B lane=col(n),
// same slot->k map; C/D col=l&15, row=(l>>4)*4+r. A from w_ind1/w_rel fp32 (cvt->bf16);
// B from bmat fp32 (cvt->bf16; rows>=24 zero). Wave-job = 64 k-rows x K=640 (48 jobs).
// Stores: packed bf16 pairs as dwords into wbT [32][3072] (k pairs are even-aligned).
__global__ __launch_bounds__(256) void prep2m(
    const float* __restrict__ w_ind1, const float* __restrict__ w_rel,
    const float* __restrict__ bmat, unsigned int* __restrict__ wbT32) {
  const int tid = threadIdx.x;
  const int l = tid & 63;
  const int w = tid >> 6;
  const int wid = blockIdx.x*4 + w;        // 48 wave-jobs
  const int R0 = wid*64;                   // k-row base
  const int ln = l & 15, lg = l >> 4;

  f32x4 acc[4][2];
#pragma unroll
  for (int i = 0; i < 4; ++i) {
    acc[i][0] = (f32x4){0.f, 0.f, 0.f, 0.f};
    acc[i][1] = (f32x4){0.f, 0.f, 0.f, 0.f};
  }

#pragma unroll 2
  for (int ks = 0; ks < 20; ++ks) {
    const int j0 = ks*32 + lg*8;           // lane's K offset (branch below is ks-uniform)
    // B fragments from fp32 bmat
    bf16x8 b0, b1;
    {
      const float* bp = bmat + ln*640 + j0;              // n = ln (always < 24)
      float4 ba = *(const float4*)bp, bb = *(const float4*)(bp + 4);
      b0[0] = f2bf(ba.x); b0[1] = f2bf(ba.y); b0[2] = f2bf(ba.z); b0[3] = f2bf(ba.w);
      b0[4] = f2bf(bb.x); b0[5] = f2bf(bb.y); b0[6] = f2bf(bb.z); b0[7] = f2bf(bb.w);
      if (ln < 8) {                                      // n = 16+ln < 24
        const float* bp1 = bmat + (16 + ln)*640 + j0;
        float4 ca = *(const float4*)bp1, cb = *(const float4*)(bp1 + 4);
        b1[0] = f2bf(ca.x); b1[1] = f2bf(ca.y); b1[2] = f2bf(ca.z); b1[3] = f2bf(ca.w);
        b1[4] = f2bf(cb.x); b1[5] = f2bf(cb.y); b1[6] = f2bf(cb.z); b1[7] = f2bf(cb.w);
      } else {
#pragma unroll
        for (int e = 0; e < 8; ++e) b1[e] = 0;
      }
    }
#pragma unroll
    for (int i = 0; i < 4; ++i) {
      int row = R0 + i*16 + ln;
      const float* ap = (ks < 4) ? (w_ind1 + (size_t)row*128 + j0)
                                 : (w_rel  + (size_t)row*512 + (j0 - 128));
      float4 xa = *(const float4*)ap, xb = *(const float4*)(ap + 4);
      bf16x8 a;
      a[0] = f2bf(xa.x); a[1] = f2bf(xa.y); a[2] = f2bf(xa.z); a[3] = f2bf(xa.w);
      a[4] = f2bf(xb.x); a[5] = f2bf(xb.y); a[6] = f2bf(xb.z); a[7] = f2bf(xb.w);
      acc[i][0] = __builtin_amdgcn_mfma_f32_16x16x32_bf16(a, b0, acc[i][0], 0, 0, 0);
      acc[i][1] = __builtin_amdgcn_mfma_f32_16x16x32_bf16(a, b1, acc[i][1], 0, 0, 0);
    }
  }

  // store packed bf16 pairs: D col = ln -> n; row = lg*4 + r -> k-local
#pragma unroll
  for (int i = 0; i < 4; ++i) {
#pragma unroll
    for (int tn = 0; tn < 2; ++tn) {
      int n = tn*16 + ln;
      int k0 = R0 + i*16 + lg*4;           // even
      size_t d = ((size_t)n*3072 + k0) >> 1;
      wbT32[d]     = f2bfu(acc[i][tn][0]) | (f2bfu(acc[i][tn][1]) << 16);
      wbT32[d + 1] = f2bfu(acc[i][tn][2]) | (f2bfu(acc[i][tn][3]) << 16);
    }
  }
}

// ---------------- kmain body (R13 verbatim): wave-job = 64 rows x 256 k ----------------
__device__ __forceinline__ void kmain_body(
    const float* __restrict__ nf, const float* __restrict__ intf,
    const unsigned short* __restrict__ wbT, float* __restrict__ ndp, float* __restrict__ edp,
    float (*red)[1600]) {
  const int tid = threadIdx.x;
  const int l = tid & 63;
  const int w = tid >> 6;
  const int wid = blockIdx.x*4 + w;
  const bool isNode = wid < 1024;

  int rg, chunk, kbase;
  if (isNode) { rg = wid >> 3; chunk = wid & 7; kbase = 0; }
  else        { int e = wid - 1024; rg = e >> 2; chunk = e & 3; kbase = 2048; }
  const int R0 = rg*64;
  const int kd0 = chunk*256;

  const int ln = l & 15, lg = l >> 4;

  const float* xp[4];
#pragma unroll
  for (int i = 0; i < 4; ++i) {
    int grow = R0 + i*16 + ln;
    const float* rp;
    if (isNode) rp = nf + (size_t)grow*2048;
    else {
      int b = grow / 28, p = grow - b*28;
      rp = intf + (size_t)(b*64 + d_pi[p]*8 + d_pj[p])*1024;
    }
    xp[i] = rp + kd0 + lg*8;
  }
  const unsigned short* wp0 = wbT + (size_t)ln*3072 + kbase + kd0 + lg*8;
  const unsigned short* wp1 = wp0 + (size_t)16*3072;

  f32x4 acc[4][2];
#pragma unroll
  for (int i = 0; i < 4; ++i) {
    acc[i][0] = (f32x4){0.f, 0.f, 0.f, 0.f};
    acc[i][1] = (f32x4){0.f, 0.f, 0.f, 0.f};
  }

#pragma unroll 2
  for (int t = 0; t < 8; ++t) {
    const int ko = t*32;
    bf16x8 b0 = *(const bf16x8*)(wp0 + ko);
    bf16x8 b1 = *(const bf16x8*)(wp1 + ko);
#pragma unroll
    for (int i = 0; i < 4; ++i) {
      float4 xa = *(const float4*)(xp[i] + ko);
      float4 xb = *(const float4*)(xp[i] + ko + 4);
      bf16x8 a;
      a[0] = f2bf(xa.x); a[1] = f2bf(xa.y); a[2] = f2bf(xa.z); a[3] = f2bf(xa.w);
      a[4] = f2bf(xb.x); a[5] = f2bf(xb.y); a[6] = f2bf(xb.z); a[7] = f2bf(xb.w);
      acc[i][0] = __builtin_amdgcn_mfma_f32_16x16x32_bf16(a, b0, acc[i][0], 0, 0, 0);
      acc[i][1] = __builtin_amdgcn_mfma_f32_16x16x32_bf16(a, b1, acc[i][1], 0, 0, 0);
    }
  }

  float* rw = red[w];
#pragma unroll
  for (int i = 0; i < 4; ++i)
#pragma unroll
    for (int tn = 0; tn < 2; ++tn) {
      int n = tn*16 + ln;
      if (n < 23) {
#pragma unroll
        for (int r = 0; r < 4; ++r)
          rw[(i*16 + lg*4 + r)*25 + n] = acc[i][tn][r];
      }
    }
  __syncthreads();
  float* outp = isNode ? (ndp + ((size_t)chunk*8192  + R0)*23)
                       : (edp + ((size_t)chunk*28672 + R0)*23);
#pragma unroll
  for (int i = 0; i < 23; ++i) {
    int g = i*64 + l;
    int r = g / 23, n = g - r*23;
    outp[g] = rw[r*25 + n];
  }
}

__global__ __launch_bounds__(256) void kmain_mfma(
    const float* __restrict__ nf, const float* __restrict__ intf,
    const unsigned short* __restrict__ wbT, float* __restrict__ ndp, float* __restrict__ edp) {
  __shared__ float red[4][1600];
  kmain_body(nf, intf, wbT, ndp, edp, red);
}

// kmain_diag x16: pins kmain's true duration (top-5 row / 16). Runs LAST.
__global__ __launch_bounds__(256) void kmain_diag(
    const float* __restrict__ nf, const float* __restrict__ intf,
    const unsigned short* __restrict__ wbT, float* __restrict__ ndp, float* __restrict__ edp) {
  __shared__ float red[4][1600];
#pragma unroll 1
  for (int rep = 0; rep < 16; ++rep) {
    kmain_body(nf, intf, wbT, ndp, edp, red);
    __syncthreads();                       // rep-safe: red reuse across reps
    asm volatile("" ::: "memory");
  }
}

// ---------------- kcombine: one batch per block; sums 8 node / 4 edge partials ----------------
__global__ __launch_bounds__(256) void kcombine(
    const float* __restrict__ ndp, const float* __restrict__ edp,
    const float* __restrict__ bbig, const int* __restrict__ opairs,
    float* __restrict__ out) {
  __shared__ float snd[184];
  __shared__ int spos[8];
  int b = blockIdx.x, tid = threadIdx.x;
  if (tid < 184) {
    int o = tid / 23, n = tid % 23;
    float s = 0.f;
#pragma unroll
    for (int c = 0; c < 8; ++c)
      s += ndp[((size_t)c*8192 + b*8 + o)*23 + n];
    snd[tid] = s;
  } else if (tid < 192) {
    int r = tid - 184;
    int oi = opairs[b*16 + r*2], oj = opairs[b*16 + r*2 + 1];
    int a = min(oi, oj), bb = max(oi, oj);
    spos[r] = 7*a - (a*(a+1))/2 + bb - 1;
  }
  __syncthreads();
  for (int g = tid; g < 644; g += 256) {
    int p = g / 23, n = g % 23;
    float ed = 0.f;
#pragma unroll
    for (int c = 0; c < 4; ++c)
      ed += edp[((size_t)c*28672 + b*28 + p)*23 + n];
    float val = 0.5f*(snd[d_pi[p]*23 + n] + snd[d_pj[p]*23 + n]) + ed + bbig[n];
    int slot = -1, below = 0;
#pragma unroll
    for (int r = 0; r < 8; ++r) {
      int pl = spos[r];
      slot = (pl == p) ? r : slot;
      below += (pl < p) ? 1 : 0;
    }
    if (n == 0) {
      out[OUT_IND + b*28 + p] = 1.f/(1.f + expf(-val));
      out[OUT_LAB + b*28 + p] = (slot >= 0) ? 1.f : 0.f;
    } else {
      int h = n - 1;
      if (slot >= 0) {
        int rr = b*8 + slot;
        if (h < 5)      out[OUT_LRP + rr*5  + h]     = val;
        else if (h < 8) out[OUT_CRP + rr*3  + (h-5)] = val;
        else            out[OUT_MRP + rr*14 + (h-8)] = val;
      } else {
        int s = p - below;
        int rr = b*20 + s;
        if (h < 5)      out[OUT_LRN + rr*5  + h]     = val;
        else if (h < 8) out[OUT_CRN + rr*3  + (h-5)] = val;
        else            out[OUT_MRN + rr*14 + (h-8)] = val;
      }
    }
  }
}

extern "C" void kernel_launch(void* const* d_in, const int* in_sizes, int n_in,
                              void* d_out, int out_size, void* d_ws, size_t ws_size,
                              hipStream_t stream) {
  const float* nf     = (const float*)d_in[0];
  const float* intf   = (const float*)d_in[1];
  const int*   opairs = (const int*)d_in[2];
  const float* w_ind1 = (const float*)d_in[3];
  const float* b_ind1 = (const float*)d_in[4];
  const float* w_ind2 = (const float*)d_in[5];
  const float* b_ind2 = (const float*)d_in[6];
  const float* w_rel  = (const float*)d_in[7];
  const float* b_rel  = (const float*)d_in[8];
  const float* w_cr   = (const float*)d_in[9];
  const float* b_cr   = (const float*)d_in[10];
  const float* w_lr   = (const float*)d_in[11];
  const float* b_lr   = (const float*)d_in[12];
  const float* w_mr   = (const float*)d_in[13];
  const float* b_mr   = (const float*)d_in[14];
  float* out = (float*)d_out;
  float* ws  = (float*)d_ws;

  float*          bmat  = ws + WS_BMAT;
  float*          bbig  = ws + WS_BBIG;
  unsigned int*   wbT32 = (unsigned int*)(ws + WS_WBT);
  unsigned short* wbT   = (unsigned short*)(ws + WS_WBT);
  float*          ndp   = ws + WS_ND;
  float*          edp   = ws + WS_ED;

  prep1<<<177, 256, 0, stream>>>(w_rel, w_ind2, w_lr, w_cr, w_mr,
                                 b_ind1, b_ind2, b_rel, b_lr, b_cr, b_mr, bmat, bbig);
  prep2m<<<12, 256, 0, stream>>>(w_ind1, w_rel, bmat, wbT32);
  kmain_mfma<<<704, 256, 0, stream>>>(nf, intf, wbT, ndp, edp);
  kcombine<<<1024, 256, 0, stream>>>(ndp, edp, bbig, opairs, out);
  kmain_diag<<<704, 256, 0, stream>>>(nf, intf, wbT, ndp, edp);  // attribution, runs last
}

// Round 20
// 110.519 us; speedup vs baseline: 5.3241x; 5.3241x over previous
//
#include <hip/hip_runtime.h>
#include <hip/hip_bf16.h>
#include <cstdint>
#include <cstddef>

// ws layout (float offsets)
#define WS_BMAT 0            // bmatT: 24*640 = 15360
#define WS_BBIG 15360        // 24 (+pad to 64)
#define WS_WBT  15424        // wbT bf16 [32][3072] = 98304 ushort = 49152 floats
#define WS_ND   64576        // 8192*23 = 188416 (FINAL, no chunks)
#define WS_ED   252992       // 28672*23 = 659456

// output offsets (floats)
#define OUT_IND 0
#define OUT_LAB 28672
#define OUT_LRP 57344
#define OUT_CRP 98304
#define OUT_MRP 122880
#define OUT_LRN 237568
#define OUT_CRN 339968
#define OUT_MRN 401408

typedef __attribute__((ext_vector_type(8))) short bf16x8;
typedef __attribute__((ext_vector_type(4))) float f32x4;

__device__ __constant__ int d_pi[28] = {0,0,0,0,0,0,0,1,1,1,1,1,1,2,2,2,2,2,3,3,3,3,4,4,4,5,5,6};
__device__ __constant__ int d_pj[28] = {1,2,3,4,5,6,7,2,3,4,5,6,7,3,4,5,6,7,4,5,6,7,5,6,7,6,7,7};

__device__ __forceinline__ float wh_at(const float* wlr, const float* wcr, const float* wmr,
                                       int j, int h) {
  return (h < 5) ? wlr[j*5 + h] : (h < 8) ? wcr[j*3 + (h-5)] : wmr[j*14 + (h-8)];
}

__device__ __forceinline__ short f2bf(float f) {
  __hip_bfloat16 h = __float2bfloat16(f);
  short s;
  __builtin_memcpy(&s, &h, 2);
  return s;
}
__device__ __forceinline__ unsigned int f2bfu(float f) {
  __hip_bfloat16 h = __float2bfloat16(f);
  unsigned short s;
  __builtin_memcpy(&s, &h, 2);
  return (unsigned int)s;
}

// ---------------- prep1: bmatT[24][640] and b_big ----------------
__global__ __launch_bounds__(256) void prep1(
    const float* __restrict__ w_rel, const float* __restrict__ w_ind2,
    const float* __restrict__ w_lr, const float* __restrict__ w_cr, const float* __restrict__ w_mr,
    const float* __restrict__ b_ind1, const float* __restrict__ b_ind2,
    const float* __restrict__ b_rel,
    const float* __restrict__ b_lr, const float* __restrict__ b_cr, const float* __restrict__ b_mr,
    float* __restrict__ bmat, float* __restrict__ bbig) {
  int bid = blockIdx.x, tid = threadIdx.x;
  if (bid < 128) {
    int m = bid;
    __shared__ float swr[512];
    const float* wr2 = w_rel + (size_t)(3072 + m)*512;
    swr[tid]       = wr2[tid];
    swr[tid + 256] = wr2[tid + 256];
    __syncthreads();
    int h = tid >> 3, q = tid & 7;
    if (h < 22) {
      float a = 0.f;
#pragma unroll 8
      for (int jj = 0; jj < 64; ++jj) {
        int j = jj*8 + q;
        a = fmaf(swr[j], wh_at(w_lr, w_cr, w_mr, j, h), a);
      }
      a += __shfl_xor(a, 1); a += __shfl_xor(a, 2); a += __shfl_xor(a, 4);
      if (q == 0) bmat[(1 + h)*640 + m] = a;
    }
    if (tid == 248) bmat[0*640 + m]  = w_ind2[m];
    if (tid == 249) bmat[23*640 + m] = 0.f;
  } else if (bid == 128) {
    __shared__ float sbrel[512];
    for (int j = tid; j < 512; j += 256) {
      float a = b_rel[j];
#pragma unroll 4
      for (int m = 0; m < 128; ++m)
        a = fmaf(b_ind1[m], w_rel[(size_t)(3072 + m)*512 + j], a);
      sbrel[j] = a;
    }
    __syncthreads();
    int h = tid >> 3, q = tid & 7;
    if (h < 22) {
      float bh = (h < 5) ? b_lr[h] : (h < 8) ? b_cr[h-5] : b_mr[h-8];
      float a = 0.f;
#pragma unroll 8
      for (int jj = 0; jj < 64; ++jj) {
        int j = jj*8 + q;
        a = fmaf(sbrel[j], wh_at(w_lr, w_cr, w_mr, j, h), a);
      }
      a += __shfl_xor(a, 1); a += __shfl_xor(a, 2); a += __shfl_xor(a, 4);
      if (q == 0) bbig[1 + h] = a + bh;
    } else if (tid >= 248) {
      int q2 = tid & 7;
      float a = 0.f;
#pragma unroll
      for (int t = 0; t < 16; ++t)
        a = fmaf(b_ind1[q2*16 + t], w_ind2[q2*16 + t], a);
      a += __shfl_xor(a, 1); a += __shfl_xor(a, 2); a += __shfl_xor(a, 4);
      if (tid == 248) bbig[0]  = a + b_ind2[0];
      if (tid == 250) bbig[23] = 0.f;
    }
  } else {
    int idx = (bid - 129)*256 + tid;
    int j = idx / 24, n = idx % 24;
    float v = (n >= 1 && n <= 22) ? wh_at(w_lr, w_cr, w_mr, j, n - 1) : 0.f;
    bmat[n*640 + 128 + j] = v;
  }
}

// ---------------- prep2m: W_big via MFMA; wave-job = 16 k-rows x K=640 (192 jobs) -------
__global__ __launch_bounds__(256) void prep2m(
    const float* __restrict__ w_ind1, const float* __restrict__ w_rel,
    const float* __restrict__ bmat, unsigned int* __restrict__ wbT32) {
  const int tid = threadIdx.x;
  const int l = tid & 63;
  const int w = tid >> 6;
  const int wid = blockIdx.x*4 + w;        // 192 wave-jobs
  const int R0 = wid*16;                   // k-row base
  const int ln = l & 15, lg = l >> 4;

  f32x4 acc0 = (f32x4){0.f, 0.f, 0.f, 0.f};
  f32x4 acc1 = (f32x4){0.f, 0.f, 0.f, 0.f};

#pragma unroll 2
  for (int ks = 0; ks < 20; ++ks) {
    const int j0 = ks*32 + lg*8;
    bf16x8 b0, b1;
    {
      const float* bp = bmat + ln*640 + j0;
      float4 ba = *(const float4*)bp, bb = *(const float4*)(bp + 4);
      b0[0] = f2bf(ba.x); b0[1] = f2bf(ba.y); b0[2] = f2bf(ba.z); b0[3] = f2bf(ba.w);
      b0[4] = f2bf(bb.x); b0[5] = f2bf(bb.y); b0[6] = f2bf(bb.z); b0[7] = f2bf(bb.w);
      if (ln < 8) {
        const float* bp1 = bmat + (16 + ln)*640 + j0;
        float4 ca = *(const float4*)bp1, cb = *(const float4*)(bp1 + 4);
        b1[0] = f2bf(ca.x); b1[1] = f2bf(ca.y); b1[2] = f2bf(ca.z); b1[3] = f2bf(ca.w);
        b1[4] = f2bf(cb.x); b1[5] = f2bf(cb.y); b1[6] = f2bf(cb.z); b1[7] = f2bf(cb.w);
      } else {
#pragma unroll
        for (int e = 0; e < 8; ++e) b1[e] = 0;
      }
    }
    int row = R0 + ln;
    const float* ap = (ks < 4) ? (w_ind1 + (size_t)row*128 + j0)
                               : (w_rel  + (size_t)row*512 + (j0 - 128));
    float4 xa = *(const float4*)ap, xb = *(const float4*)(ap + 4);
    bf16x8 a;
    a[0] = f2bf(xa.x); a[1] = f2bf(xa.y); a[2] = f2bf(xa.z); a[3] = f2bf(xa.w);
    a[4] = f2bf(xb.x); a[5] = f2bf(xb.y); a[6] = f2bf(xb.z); a[7] = f2bf(xb.w);
    acc0 = __builtin_amdgcn_mfma_f32_16x16x32_bf16(a, b0, acc0, 0, 0, 0);
    acc1 = __builtin_amdgcn_mfma_f32_16x16x32_bf16(a, b1, acc1, 0, 0, 0);
  }

  // D col = ln -> n; row = lg*4 + r -> k-local; packed bf16-pair dword stores
#pragma unroll
  for (int tn = 0; tn < 2; ++tn) {
    f32x4 av = tn ? acc1 : acc0;
    int n = tn*16 + ln;
    int k0 = R0 + lg*4;                    // even
    size_t d = ((size_t)n*3072 + k0) >> 1;
    wbT32[d]     = f2bfu(av[0]) | (f2bfu(av[1]) << 16);
    wbT32[d + 1] = f2bfu(av[2]) | (f2bfu(av[3]) << 16);
  }
}

// ---------------- kmain: wave-job = 16 rows x FULL K (no chunking); final outputs -------
// 512 node jobs (K=2048) + 1792 edge jobs (K=1024) = 2304 jobs = 576 blocks.
// A: X fp32 from global, cvt->bf16. B: wbT bf16 (L2-resident).
// C/D: col=l&15 (n), row=(l>>4)*4+r (job row). Epilogue: per-wave LDS transpose -> store.
__global__ __launch_bounds__(256) void kmain_mfma(
    const float* __restrict__ nf, const float* __restrict__ intf,
    const unsigned short* __restrict__ wbT, float* __restrict__ ndp, float* __restrict__ edp) {
  __shared__ float red[4][400];            // per-wave 16x25 transpose buffers
  const int tid = threadIdx.x;
  const int l = tid & 63;
  const int w = tid >> 6;
  const int wid = blockIdx.x*4 + w;        // 2304 wave-jobs
  const bool isNode = wid < 512;

  int R0, nsteps, kbase;
  float* outp;
  if (isNode) { R0 = wid*16;          nsteps = 64; kbase = 0;    outp = ndp + (size_t)R0*23; }
  else        { int e = wid - 512; R0 = e*16; nsteps = 32; kbase = 2048; outp = edp + (size_t)R0*23; }

  const int ln = l & 15, lg = l >> 4;

  const float* xp;
  {
    int grow = R0 + ln;
    if (isNode) xp = nf + (size_t)grow*2048 + lg*8;
    else {
      int b = grow / 28, p = grow - b*28;
      xp = intf + (size_t)(b*64 + d_pi[p]*8 + d_pj[p])*1024 + lg*8;
    }
  }
  const unsigned short* wp0 = wbT + (size_t)ln*3072 + kbase + lg*8;
  const unsigned short* wp1 = wp0 + (size_t)16*3072;

  f32x4 acc0 = (f32x4){0.f, 0.f, 0.f, 0.f};
  f32x4 acc1 = (f32x4){0.f, 0.f, 0.f, 0.f};

#pragma unroll 4
  for (int t = 0; t < nsteps; ++t) {
    const int ko = t*32;
    bf16x8 b0 = *(const bf16x8*)(wp0 + ko);
    bf16x8 b1 = *(const bf16x8*)(wp1 + ko);
    float4 xa = *(const float4*)(xp + ko);
    float4 xb = *(const float4*)(xp + ko + 4);
    bf16x8 a;
    a[0] = f2bf(xa.x); a[1] = f2bf(xa.y); a[2] = f2bf(xa.z); a[3] = f2bf(xa.w);
    a[4] = f2bf(xb.x); a[5] = f2bf(xb.y); a[6] = f2bf(xb.z); a[7] = f2bf(xb.w);
    acc0 = __builtin_amdgcn_mfma_f32_16x16x32_bf16(a, b0, acc0, 0, 0, 0);
    acc1 = __builtin_amdgcn_mfma_f32_16x16x32_bf16(a, b1, acc1, 0, 0, 0);
  }

  // epilogue: per-wave LDS transpose (pitch 25) -> coalesced 368-float store
  float* rw = red[w];
#pragma unroll
  for (int tn = 0; tn < 2; ++tn) {
    int n = tn*16 + ln;
    if (n < 23) {
      f32x4 av = tn ? acc1 : acc0;
#pragma unroll
      for (int r = 0; r < 4; ++r)
        rw[(lg*4 + r)*25 + n] = av[r];
    }
  }
  __syncthreads();
  for (int g = l; g < 16*23; g += 64) {
    int r = g / 23, n = g - r*23;
    outp[g] = rw[r*25 + n];
  }
}

// ---------------- kcombine: one batch per block; direct reads (no partial sums) ---------
__global__ __launch_bounds__(256) void kcombine(
    const float* __restrict__ ndp, const float* __restrict__ edp,
    const float* __restrict__ bbig, const int* __restrict__ opairs,
    float* __restrict__ out) {
  __shared__ float snd[184];
  __shared__ int spos[8];
  int b = blockIdx.x, tid = threadIdx.x;
  if (tid < 184) snd[tid] = ndp[(size_t)b*184 + tid];      // (b*8+o)*23+n, contiguous
  else if (tid < 192) {
    int r = tid - 184;
    int oi = opairs[b*16 + r*2], oj = opairs[b*16 + r*2 + 1];
    int a = min(oi, oj), bb = max(oi, oj);
    spos[r] = 7*a - (a*(a+1))/2 + bb - 1;
  }
  __syncthreads();
  for (int g = tid; g < 644; g += 256) {
    int p = g / 23, n = g % 23;
    float ed = edp[((size_t)b*28 + p)*23 + n];
    float val = 0.5f*(snd[d_pi[p]*23 + n] + snd[d_pj[p]*23 + n]) + ed + bbig[n];
    int slot = -1, below = 0;
#pragma unroll
    for (int r = 0; r < 8; ++r) {
      int pl = spos[r];
      slot = (pl == p) ? r : slot;
      below += (pl < p) ? 1 : 0;
    }
    if (n == 0) {
      out[OUT_IND + b*28 + p] = 1.f/(1.f + expf(-val));
      out[OUT_LAB + b*28 + p] = (slot >= 0) ? 1.f : 0.f;
    } else {
      int h = n - 1;
      if (slot >= 0) {
        int rr = b*8 + slot;
        if (h < 5)      out[OUT_LRP + rr*5  + h]     = val;
        else if (h < 8) out[OUT_CRP + rr*3  + (h-5)] = val;
        else            out[OUT_MRP + rr*14 + (h-8)] = val;
      } else {
        int s = p - below;
        int rr = b*20 + s;
        if (h < 5)      out[OUT_LRN + rr*5  + h]     = val;
        else if (h < 8) out[OUT_CRN + rr*3  + (h-5)] = val;
        else            out[OUT_MRN + rr*14 + (h-8)] = val;
      }
    }
  }
}

extern "C" void kernel_launch(void* const* d_in, const int* in_sizes, int n_in,
                              void* d_out, int out_size, void* d_ws, size_t ws_size,
                              hipStream_t stream) {
  const float* nf     = (const float*)d_in[0];
  const float* intf   = (const float*)d_in[1];
  const int*   opairs = (const int*)d_in[2];
  const float* w_ind1 = (const float*)d_in[3];
  const float* b_ind1 = (const float*)d_in[4];
  const float* w_ind2 = (const float*)d_in[5];
  const float* b_ind2 = (const float*)d_in[6];
  const float* w_rel  = (const float*)d_in[7];
  const float* b_rel  = (const float*)d_in[8];
  const float* w_cr   = (const float*)d_in[9];
  const float* b_cr   = (const float*)d_in[10];
  const float* w_lr   = (const float*)d_in[11];
  const float* b_lr   = (const float*)d_in[12];
  const float* w_mr   = (const float*)d_in[13];
  const float* b_mr   = (const float*)d_in[14];
  float* out = (float*)d_out;
  float* ws  = (float*)d_ws;

  float*          bmat  = ws + WS_BMAT;
  float*          bbig  = ws + WS_BBIG;
  unsigned int*   wbT32 = (unsigned int*)(ws + WS_WBT);
  unsigned short* wbT   = (unsigned short*)(ws + WS_WBT);
  float*          ndp   = ws + WS_ND;
  float*          edp   = ws + WS_ED;

  prep1<<<177, 256, 0, stream>>>(w_rel, w_ind2, w_lr, w_cr, w_mr,
                                 b_ind1, b_ind2, b_rel, b_lr, b_cr, b_mr, bmat, bbig);
  prep2m<<<48, 256, 0, stream>>>(w_ind1, w_rel, bmat, wbT32);
  kmain_mfma<<<576, 256, 0, stream>>>(nf, intf, wbT, ndp, edp);
  kcombine<<<1024, 256, 0, stream>>>(ndp, edp, bbig, opairs, out);
}